// Round 1
// baseline (43.568 us; speedup 1.0000x reference)
//
#include <hip/hip_runtime.h>

constexpr int T_TOTAL = 100000;
constexpr int RANK    = 128;
constexpr int W       = 11;
constexpr int PAD     = 5;      // (W-1)/2
constexpr int T_TILE  = 64;
constexpr int ROWS    = T_TILE + W - 1;   // 74
constexpr int BLOCK   = 256;

__global__ __launch_bounds__(BLOCK) void attn_win_kernel(const float* __restrict__ in,
                                                         float* __restrict__ out) {
    __shared__ float lds[ROWS][RANK];
    const int t0  = blockIdx.x * T_TILE;
    const int tid = threadIdx.x;

    // ---- Stage rows [t0-PAD, t0+T_TILE+PAD) into LDS, zero-fill out-of-range ----
    const int n4 = ROWS * (RANK / 4);   // 74*32 = 2368 float4 elements
    for (int idx = tid; idx < n4; idx += BLOCK) {
        const int row  = idx >> 5;      // idx / 32
        const int c4   = idx & 31;
        const int grow = t0 - PAD + row;
        float4 v = make_float4(0.f, 0.f, 0.f, 0.f);
        if (grow >= 0 && grow < T_TOTAL)
            v = *reinterpret_cast<const float4*>(in + (size_t)grow * RANK + c4 * 4);
        *reinterpret_cast<float4*>(&lds[row][c4 * 4]) = v;
    }
    __syncthreads();

    // ---- Compute: 4 waves, each wave = 4 groups of 16 lanes, group owns one t ----
    const int wave  = tid >> 6;
    const int lane  = tid & 63;
    const int g     = lane >> 4;   // group in wave
    const int sub   = lane & 15;   // lane in group
    const int rbase = sub * 8;     // 8 floats per lane covers RANK=128

    #pragma unroll 1
    for (int it = 0; it < T_TILE / 16; ++it) {
        const int t_local = wave * 16 + it * 4 + g;
        const int t       = t0 + t_local;

        // x = time_factor[t][rbase .. rbase+7]  (lds row t_local+PAD)
        const float4 x0 = *reinterpret_cast<const float4*>(&lds[t_local + PAD][rbase]);
        const float4 x1 = *reinterpret_cast<const float4*>(&lds[t_local + PAD][rbase + 4]);

        float b[W][8];
        float c[W];
        #pragma unroll
        for (int j = 0; j < W; ++j) {
            const float4 b0 = *reinterpret_cast<const float4*>(&lds[t_local + j][rbase]);
            const float4 b1 = *reinterpret_cast<const float4*>(&lds[t_local + j][rbase + 4]);
            b[j][0] = b0.x; b[j][1] = b0.y; b[j][2] = b0.z; b[j][3] = b0.w;
            b[j][4] = b1.x; b[j][5] = b1.y; b[j][6] = b1.z; b[j][7] = b1.w;
            float s = b0.x * x0.x + b0.y * x0.y + b0.z * x0.z + b0.w * x0.w
                    + b1.x * x1.x + b1.y * x1.y + b1.z * x1.z + b1.w * x1.w;
            // reduce across the 16-lane group (xor masks 1,2,4,8 stay in-group)
            s += __shfl_xor(s, 1);
            s += __shfl_xor(s, 2);
            s += __shfl_xor(s, 4);
            s += __shfl_xor(s, 8);
            c[j] = s;
        }

        // softmax over the 11 window scores (redundant per-lane, branch-free)
        float m = c[0];
        #pragma unroll
        for (int j = 1; j < W; ++j) m = fmaxf(m, c[j]);
        float sum = 0.f;
        #pragma unroll
        for (int j = 0; j < W; ++j) { c[j] = __expf(c[j] - m); sum += c[j]; }
        const float inv = 1.f / sum;

        float acc[8] = {0.f, 0.f, 0.f, 0.f, 0.f, 0.f, 0.f, 0.f};
        #pragma unroll
        for (int j = 0; j < W; ++j) {
            const float p = c[j] * inv;
            #pragma unroll
            for (int k = 0; k < 8; ++k) acc[k] = fmaf(p, b[j][k], acc[k]);
        }

        if (t < T_TOTAL) {
            float* op = out + (size_t)t * RANK + rbase;
            *reinterpret_cast<float4*>(op)     = make_float4(acc[0], acc[1], acc[2], acc[3]);
            *reinterpret_cast<float4*>(op + 4) = make_float4(acc[4], acc[5], acc[6], acc[7]);
        }
    }
}

extern "C" void kernel_launch(void* const* d_in, const int* in_sizes, int n_in,
                              void* d_out, int out_size, void* d_ws, size_t ws_size,
                              hipStream_t stream) {
    const float* in  = (const float*)d_in[0];
    float*       out = (float*)d_out;
    const int grid = (T_TOTAL + T_TILE - 1) / T_TILE;   // 1563
    attn_win_kernel<<<grid, BLOCK, 0, stream>>>(in, out);
}

// Round 2
// 37.324 us; speedup vs baseline: 1.1673x; 1.1673x over previous
//
#include <hip/hip_runtime.h>

constexpr int T_TOTAL = 100000;
constexpr int RANK    = 128;
constexpr int W       = 11;
constexpr int PAD     = 5;      // (W-1)/2
constexpr int T_TILE  = 64;
constexpr int ROWS    = T_TILE + W - 1;   // 74
constexpr int BLOCK   = 256;
constexpr int LDSP    = RANK + 4;  // +16B/row: rotate banks by 4 each row -> balanced b128 phases

// 16-lane sum+broadcast butterfly on the VALU pipe (DPP), not LDS (ds_swizzle).
// CTRL: 0xB1 quad_perm(1,0,3,2)=xor1, 0x4E quad_perm(2,3,0,1)=xor2,
//       0x141 row_half_mirror (pairs across 4-groups), 0x140 row_mirror (across 8-groups).
template <int CTRL>
__device__ __forceinline__ float dpp_radd(float v) {
    int o = __builtin_amdgcn_update_dpp(0, __float_as_int(v), CTRL, 0xF, 0xF, true);
    return v + __int_as_float(o);
}

__global__ __launch_bounds__(BLOCK) void attn_win_kernel(const float* __restrict__ in,
                                                         float* __restrict__ out) {
    __shared__ float lds[ROWS][LDSP];
    const int t0  = blockIdx.x * T_TILE;
    const int tid = threadIdx.x;

    // ---- Stage rows [t0-PAD, t0+T_TILE+PAD) into LDS, zero-fill out-of-range ----
    const int n4 = ROWS * (RANK / 4);   // 74*32 = 2368 float4 chunks
    for (int idx = tid; idx < n4; idx += BLOCK) {
        const int row  = idx >> 5;
        const int c4   = idx & 31;
        const int grow = t0 - PAD + row;
        float4 v = make_float4(0.f, 0.f, 0.f, 0.f);
        if (grow >= 0 && grow < T_TOTAL)
            v = *reinterpret_cast<const float4*>(in + (size_t)grow * RANK + c4 * 4);
        *reinterpret_cast<float4*>(&lds[row][c4 * 4]) = v;
    }
    __syncthreads();

    // ---- Compute: 16-lane group owns one t; lane owns 8 r's; online softmax ----
    const int wave  = tid >> 6;
    const int lane  = tid & 63;
    const int g     = lane >> 4;
    const int sub   = lane & 15;
    const int rbase = sub * 8;
    constexpr float LOG2E = 1.4426950408889634f;

    #pragma unroll 1
    for (int it = 0; it < T_TILE / 16; ++it) {
        const int t_local = wave * 16 + it * 4 + g;
        const int t       = t0 + t_local;

        const float4 x0 = *reinterpret_cast<const float4*>(&lds[t_local + PAD][rbase]);
        const float4 x1 = *reinterpret_cast<const float4*>(&lds[t_local + PAD][rbase + 4]);

        float m   = -1e30f;
        float sum = 0.f;
        float acc[8] = {0.f, 0.f, 0.f, 0.f, 0.f, 0.f, 0.f, 0.f};

        #pragma unroll
        for (int j = 0; j < W; ++j) {
            const float4 b0 = *reinterpret_cast<const float4*>(&lds[t_local + j][rbase]);
            const float4 b1 = *reinterpret_cast<const float4*>(&lds[t_local + j][rbase + 4]);
            float s = b0.x * x0.x + b0.y * x0.y + b0.z * x0.z + b0.w * x0.w
                    + b1.x * x1.x + b1.y * x1.y + b1.z * x1.z + b1.w * x1.w;
            // 16-lane reduce+broadcast, all on VALU
            s = dpp_radd<0xB1>(s);
            s = dpp_radd<0x4E>(s);
            s = dpp_radd<0x141>(s);
            s = dpp_radd<0x140>(s);
            s *= LOG2E;   // work in exp2 domain

            const float mn   = fmaxf(m, s);
            const float corr = exp2f(m - mn);   // first iter: exp2(-huge)=0
            const float w    = exp2f(s - mn);
            m   = mn;
            sum = sum * corr + w;
            acc[0] = acc[0] * corr + w * b0.x;
            acc[1] = acc[1] * corr + w * b0.y;
            acc[2] = acc[2] * corr + w * b0.z;
            acc[3] = acc[3] * corr + w * b0.w;
            acc[4] = acc[4] * corr + w * b1.x;
            acc[5] = acc[5] * corr + w * b1.y;
            acc[6] = acc[6] * corr + w * b1.z;
            acc[7] = acc[7] * corr + w * b1.w;
        }

        const float inv = 1.f / sum;
        if (t < T_TOTAL) {
            float* op = out + (size_t)t * RANK + rbase;
            *reinterpret_cast<float4*>(op) =
                make_float4(acc[0] * inv, acc[1] * inv, acc[2] * inv, acc[3] * inv);
            *reinterpret_cast<float4*>(op + 4) =
                make_float4(acc[4] * inv, acc[5] * inv, acc[6] * inv, acc[7] * inv);
        }
    }
}

extern "C" void kernel_launch(void* const* d_in, const int* in_sizes, int n_in,
                              void* d_out, int out_size, void* d_ws, size_t ws_size,
                              hipStream_t stream) {
    const float* in  = (const float*)d_in[0];
    float*       out = (float*)d_out;
    const int grid = (T_TOTAL + T_TILE - 1) / T_TILE;   // 1563
    attn_win_kernel<<<grid, BLOCK, 0, stream>>>(in, out);
}